// Round 13
// baseline (62.032 us; speedup 1.0000x reference)
//
#include <hip/hip_runtime.h>

// NT-Xent loss, fused + block-triangular: S = zn8 zn8^T is symmetric exactly
// (FP products commute, same k-order); rowsum_i exp = colsum_i exp.
// One block = one 128x128 tile (rb,cb), cb>=rb; grid = 64*65/2 = 2080.
// Off-diag blocks: tile exps -> rsum[cb][rows] (row sums) and, via in-block
// column reduction, tsum[rb][cols] (transpose rows). Diag blocks: full square,
// diagonal masked, no transpose term (row sums already cover both triangles).
// Positive pair S[i][i+4096]: block cb==rb+32 writes pos[i] AND pos[i+4096].
// nll_r = -pos_r + 2 + log(sum of 64 slots); out = mean(nll).
// Inner machinery (fp8 e4m3, LDS stage + (col&3)<<5 swizzle, fragments,
// 32-VGPR pinned A) = R11 verified code unchanged. No zero kernel: every
// slot read by nll has exactly one writer.

#define NHALF 4096
#define N2 8192
#define D 256
#define NBLK 2080

typedef __attribute__((ext_vector_type(4))) float f32x4;

__device__ __forceinline__ unsigned char f2fp8(float f) {
  // OCP e4m3fn, RNE; inputs |f| <= 1 (normalized rows): no sat/NaN path.
  unsigned int u = __float_as_uint(f);
  unsigned char s = (unsigned char)((u >> 24) & 0x80u);
  int e = (int)((u >> 23) & 0xffu) - 127;
  unsigned int m = u & 0x7fffffu;
  if (e >= -6) {
    unsigned int r = m + 0x7ffffu + ((m >> 20) & 1u);
    if (r >= 0x800000u) { r = 0; ++e; } else r >>= 20;
    return (unsigned char)(s | (unsigned int)((e + 7) << 3) | r);
  }
  int q = (int)rintf(fabsf(f) * 512.0f);
  return (unsigned char)(s | (unsigned int)q);
}

__device__ __forceinline__ void gload_lds16(const void* g, void* l) {
  __builtin_amdgcn_global_load_lds(
      (const __attribute__((address_space(1))) unsigned int*)g,
      (__attribute__((address_space(3))) unsigned int*)l, 16, 0, 0);
}

// blocks with row-tile < rb: cum(rb) = 64*rb - rb*(rb-1)/2
__device__ __forceinline__ int cumblk(int rb) {
  return 64 * rb - (rb * (rb - 1)) / 2;
}

// ---------------- Kernel 1: row-normalize to fp8 ----------------
__global__ __launch_bounds__(256) void norm_kernel(const float* __restrict__ z1,
                                                   const float* __restrict__ z2,
                                                   unsigned char* __restrict__ zn8) {
  const int lane = threadIdx.x & 63;
  const int row = blockIdx.x * 4 + (threadIdx.x >> 6);
  const float* src = (row < NHALF) ? (z1 + (size_t)row * D)
                                   : (z2 + (size_t)(row - NHALF) * D);
  const float4 v = *(const float4*)(src + lane * 4);
  float ss = v.x * v.x + v.y * v.y + v.z * v.z + v.w * v.w;
  #pragma unroll
  for (int m = 1; m < 64; m <<= 1) ss += __shfl_xor(ss, m);
  const float inv = 1.0f / fmaxf(sqrtf(ss), 1e-8f);
  unsigned int o = (unsigned int)f2fp8(v.x * inv) |
                   ((unsigned int)f2fp8(v.y * inv) << 8) |
                   ((unsigned int)f2fp8(v.z * inv) << 16) |
                   ((unsigned int)f2fp8(v.w * inv) << 24);
  *(unsigned int*)(zn8 + (size_t)row * D + lane * 4) = o;
}

// ---------------- Kernel 2: block-triangular fused Gram + exp-sums ----------------
__global__ __launch_bounds__(256, 4) void simblk_kernel(const unsigned char* __restrict__ zn8,
                                                        float* __restrict__ rsum,
                                                        float* __restrict__ tsum,
                                                        float* __restrict__ pos_ws) {
  __shared__ __align__(16) char bsm[32768];  // 2 x 16 KB (64 cols x 256 B)
  __shared__ float colred[4][128];
  const int lane = threadIdx.x & 63;
  const int wave = threadIdx.x >> 6;
  const int r16 = lane & 15;
  const int h = lane >> 4;  // 0..3

  // Decode (rb, cb) from flat triangular index.
  const int idx = blockIdx.x;
  int rb = (int)((129.0f - sqrtf(16641.0f - 8.0f * (float)idx)) * 0.5f);
  if (rb < 0) rb = 0;
  if (rb > 63) rb = 63;
  while (rb < 63 && cumblk(rb + 1) <= idx) ++rb;
  while (rb > 0 && cumblk(rb) > idx) --rb;
  const int cb = rb + (idx - cumblk(rb));
  const int rowbase = rb * 128 + wave * 32;
  const int colbase = cb * 128;
  const bool diag = (rb == cb);

  // A fragments: 2 stripes x 8 K-steps, 8B/lane = 32 VGPR (R11-verified).
  long a[2][8];
  #pragma unroll
  for (int st = 0; st < 2; ++st) {
    const unsigned char* ap = zn8 + (size_t)(rowbase + st * 16 + r16) * D + h * 8;
    #pragma unroll
    for (int s = 0; s < 8; ++s) a[st][s] = *(const long*)(ap + s * 32);
  }
  #pragma unroll
  for (int st = 0; st < 2; ++st)
    #pragma unroll
    for (int s = 0; s < 8; ++s) asm volatile("" : "+v"(a[st][s]));

  float lsum[2][4];
  #pragma unroll
  for (int st = 0; st < 2; ++st)
    #pragma unroll
    for (int g = 0; g < 4; ++g) lsum[st][g] = 0.0f;

  // Stage 64 cols (16 KB) into LDS buffer. Linear y in [0,16384):
  // col = y>>8, inner = y&255; src inner ^= (col&3)<<5 (involution; matches
  // the swizzled ds_read below; 16B-aligned: XOR touches bits 5-6 only).
  auto stage = [&](int buf, int ph) {
    #pragma unroll
    for (int s = 0; s < 4; ++s) {
      const int y = s * 4096 + wave * 1024 + lane * 16;
      const int col = y >> 8;
      const int inner = (y & 255) ^ ((col & 3) << 5);
      const void* gp = zn8 + (size_t)(colbase + ph * 64 + col) * D + inner;
      void* lp = bsm + buf * 16384 + s * 4096 + wave * 1024;  // +lane*16 by HW
      gload_lds16(gp, lp);
    }
  };

  stage(0, 0);
  __syncthreads();
  #pragma unroll
  for (int ph = 0; ph < 2; ++ph) {
    if (ph == 0) stage(1, 1);  // DMA overlaps compute
    const char* base = bsm + ph * 16384;
    #pragma unroll
    for (int j = 0; j < 4; ++j) {
      const int ct16 = cb * 8 + ph * 4 + j;
      const char* tb = base + j * 4096 + r16 * 256;
      const int sw = (r16 & 3) << 5;
      f32x4 acc0 = (f32x4){0.f, 0.f, 0.f, 0.f};
      f32x4 acc1 = (f32x4){0.f, 0.f, 0.f, 0.f};
      #pragma unroll
      for (int s = 0; s < 8; ++s) {
        const long b = *(const long*)(tb + ((s * 32 + h * 8) ^ sw));
        acc0 = __builtin_amdgcn_mfma_f32_16x16x32_fp8_fp8(a[0][s], b, acc0, 0, 0, 0);
        acc1 = __builtin_amdgcn_mfma_f32_16x16x32_fp8_fp8(a[1][s], b, acc1, 0, 0, 0);
      }
      float cpart = 0.0f;
      #pragma unroll
      for (int st = 0; st < 2; ++st) {
        const f32x4& acc = st ? acc1 : acc0;
        const int rt16 = rb * 8 + wave * 2 + st;
        const bool isd = (ct16 == rt16);          // only in diag blocks
        const bool isp = (ct16 == rt16 + 256);    // only when cb == rb+32
        #pragma unroll
        for (int g = 0; g < 4; ++g) {
          const int rl = (h << 2) + g;            // local row 0..15
          float e = __expf(fmaf(acc[g], 2.0f, -2.0f));
          if (isd && r16 == rl) e = 0.0f;         // mask self-similarity
          if (isp && r16 == rl) {
            const int row = rowbase + st * 16 + rl;
            const float s2 = acc[g] * 2.0f;
            pos_ws[row] = s2;
            pos_ws[row + NHALF] = s2;             // symmetric positive
          }
          lsum[st][g] += e;
          cpart += e;
        }
      }
      // column partial over this wave's 32 rows (sum the 4 h-groups)
      cpart += __shfl_xor(cpart, 16);
      cpart += __shfl_xor(cpart, 32);
      if (h == 0) colred[wave][ph * 64 + j * 16 + r16] = cpart;
    }
    __syncthreads();  // drains DMA + LDS reads; publishes colred
  }

  // Transpose contribution: tsum[rb][col] (skip diag: row sums already
  // cover both triangles of the diagonal tile).
  if (!diag && threadIdx.x < 128) {
    const int c = threadIdx.x;
    const float sm = colred[0][c] + colred[1][c] + colred[2][c] + colred[3][c];
    tsum[(size_t)rb * N2 + colbase + c] = sm;
  }

  // Row sums -> rsum[cb][row] (slot-major for coalesced nll reads).
  #pragma unroll
  for (int st = 0; st < 2; ++st)
    #pragma unroll
    for (int g = 0; g < 4; ++g) {
      #pragma unroll
      for (int m = 1; m < 16; m <<= 1)
        lsum[st][g] += __shfl_xor(lsum[st][g], m);
    }
  if (r16 == 0) {
    #pragma unroll
    for (int st = 0; st < 2; ++st)
      #pragma unroll
      for (int g = 0; g < 4; ++g) {
        const int row = rowbase + st * 16 + (h << 2) + g;
        rsum[(size_t)cb * N2 + row] = lsum[st][g];
      }
  }
}

// ---------------- Kernel 3a: per-row nll + per-block partial sum ----------------
// Row r: slots s>=rb_r come from rsum[s][r] (blocks (rb_r,s)); slots s<rb_r
// from tsum[s][r] (blocks (s, rb_r), transpose). Exactly 64 slots, each with
// a unique writer -> deterministic, no zeroing needed.
__global__ __launch_bounds__(256) void nll_kernel(const float* __restrict__ rsum,
                                                  const float* __restrict__ tsum,
                                                  const float* __restrict__ pos_ws,
                                                  float* __restrict__ partial) {
  const int r = blockIdx.x * 256 + threadIdx.x;
  const int rb_r = r >> 7;
  float t = 0.0f;
  #pragma unroll
  for (int s = 0; s < 64; ++s) {
    const float* b = (s >= rb_r) ? rsum : tsum;
    t += b[(size_t)s * N2 + r];
  }
  float nll = -pos_ws[r] + 2.0f + __logf(t);
  #pragma unroll
  for (int m = 1; m < 64; m <<= 1) nll += __shfl_xor(nll, m);
  __shared__ float red[4];
  const int lane = threadIdx.x & 63;
  const int wave = threadIdx.x >> 6;
  if (lane == 0) red[wave] = nll;
  __syncthreads();
  if (threadIdx.x == 0) partial[blockIdx.x] = red[0] + red[1] + red[2] + red[3];
}

// ---------------- Kernel 3b: final mean ----------------
__global__ __launch_bounds__(64) void final_kernel(const float* __restrict__ partial,
                                                   float* __restrict__ out) {
  const int lane = threadIdx.x;
  float v = (lane < 32) ? partial[lane] : 0.0f;
  #pragma unroll
  for (int m = 1; m < 64; m <<= 1) v += __shfl_xor(v, m);
  if (lane == 0) out[0] = v * (1.0f / (float)N2);
}

extern "C" void kernel_launch(void* const* d_in, const int* in_sizes, int n_in,
                              void* d_out, int out_size, void* d_ws, size_t ws_size,
                              hipStream_t stream) {
  const float* z1 = (const float*)d_in[0];
  const float* z2 = (const float*)d_in[1];
  float* out = (float*)d_out;

  char* ws = (char*)d_ws;
  unsigned char* zn8 = (unsigned char*)ws;                  // 8192*256 = 2 MB
  float* rsum = (float*)(ws + (size_t)N2 * D);              // 64*8192*4 = 2 MB
  float* tsum = rsum + (size_t)64 * N2;                     // 2 MB
  float* pos_ws = tsum + (size_t)64 * N2;                   // 8192*4 = 32 KB
  float* partial = pos_ws + N2;                             // 32 floats

  hipLaunchKernelGGL(norm_kernel, dim3(N2 / 4), dim3(256), 0, stream, z1, z2, zn8);
  hipLaunchKernelGGL(simblk_kernel, dim3(NBLK), dim3(256), 0, stream,
                     zn8, rsum, tsum, pos_ws);
  hipLaunchKernelGGL(nll_kernel, dim3(N2 / 256), dim3(256), 0, stream,
                     rsum, tsum, pos_ws, partial);
  hipLaunchKernelGGL(final_kernel, dim3(1), dim3(64), 0, stream, partial, out);
}